// Round 20
// baseline (61.323 us; speedup 1.0000x reference)
//
#include <hip/hip_runtime.h>

#define NPTS     16384
#define G        20
#define G2       400
#define ORIGIN   -5.0f
#define CELL     0.5f
#define INV_CELL 2.0f
#define D2MAX    0.25f     // EPS^2 sentinel; also the prune radius^2

#define KNN_GRID  2048     // 256-thread blocks; 8 half-wave queries each
#define KNN_BLOCK 256

// ---- ws layout (bytes) ----
#define OFF_COUNTS  0u         // u32[8192]
#define OFF_CURSORS 32768u     // u32[8192]
#define OFF_STARTS  65536u     // u32[8192] (column-contiguous compact layout)
#define OFF_GCUR    98304u     // u32 global allocation cursor
#define OFF_PART    131072u    // float[16384] per-QUERY partials (fixed order)
#define OFF_PTS     262144u    // float4[16384] compact; .w = original index
#define WS_REQUIRED 524288u

__device__ __forceinline__ int cell_coord(float v) {
  int c = (int)floorf((v - ORIGIN) * INV_CELL);
  return min(max(c, 0), G - 1);
}

// K0: zero counts + cursors + starts head (96 KB) + gcur.
__global__ __launch_bounds__(256) void zero_kernel(unsigned char* ws) {
  uint4* p = (uint4*)ws;
  const int i = blockIdx.x * 256 + threadIdx.x;   // 24 blocks -> 6144 x 16 B
  p[i] = make_uint4(0u, 0u, 0u, 0u);
  if (i == 0) *(unsigned*)(ws + OFF_GCUR) = 0u;
}

// K1: histogram.
__global__ __launch_bounds__(256) void hist_kernel(const float* __restrict__ q,
                                                   unsigned char* ws) {
  unsigned* counts = (unsigned*)(ws + OFF_COUNTS);
  const int i = blockIdx.x * 256 + threadIdx.x;   // 16384 threads
  const int c = (cell_coord(q[3 * i]) * G + cell_coord(q[3 * i + 1])) * G
              + cell_coord(q[3 * i + 2]);
  atomicAdd(counts + c, 1u);
}

// K2: SCAN-FREE compact allocation (atomicAdd region per (x,y) column,
// serial z-prefix inside). Order nondeterministic -> harmless.
__global__ __launch_bounds__(256) void colalloc_kernel(unsigned char* ws) {
  const unsigned* counts = (const unsigned*)(ws + OFF_COUNTS);
  unsigned*       starts = (unsigned*)(ws + OFF_STARTS);
  unsigned*       gcur   = (unsigned*)(ws + OFF_GCUR);
  const int i = blockIdx.x * 256 + threadIdx.x;   // 2 blocks; i < 400 active
  if (i < G2) {
    unsigned c20[G];
    unsigned tot = 0;
#pragma unroll
    for (int z = 0; z < G; ++z) { c20[z] = counts[i * G + z]; tot += c20[z]; }
    unsigned base = atomicAdd(gcur, tot);
#pragma unroll
    for (int z = 0; z < G; ++z) { starts[i * G + z] = base; base += c20[z]; }
  }
}

// K3: scatter into the compact layout; stash original index in .w.
__global__ __launch_bounds__(256) void scatter_kernel(const float* __restrict__ q,
                                                      unsigned char* ws) {
  const unsigned* starts  = (const unsigned*)(ws + OFF_STARTS);
  unsigned*       cursors = (unsigned*)(ws + OFF_CURSORS);
  float4*         pts     = (float4*)(ws + OFF_PTS);
  const int i = blockIdx.x * 256 + threadIdx.x;   // 16384 threads
  const float x = q[3 * i], y = q[3 * i + 1], z = q[3 * i + 2];
  const int c = (cell_coord(x) * G + cell_coord(y)) * G + cell_coord(z);
  const unsigned pos = starts[c] + atomicAdd(cursors + c, 1u);
  pts[pos] = make_float4(x, y, z, __int_as_float(i));
}

// K4: 32 LANES PER QUERY (half-wave groups), 8 queries per 256-thread block.
// Per query: ball-pruned z-contiguous column ranges FLATTENED into one
// virtual list (off[r] = rs[r]-cum[r]; addr = f + off[select]); inner loop
// processes 128 flat candidates per iteration with 4 INDEPENDENT loads per
// lane in flight (MLP=4). Per-lane sorted top-5; per-half butterfly
// extract-8; part[original index] -> fixed-order deterministic reduce.
__global__ __launch_bounds__(KNN_BLOCK, 4) void knn_kernel(unsigned char* ws) {
  const unsigned* counts = (const unsigned*)(ws + OFF_COUNTS);
  const unsigned* starts = (const unsigned*)(ws + OFF_STARTS);
  const float4*   pts    = (const float4*)(ws + OFF_PTS);
  float*          part   = (float*)(ws + OFF_PART);

  const int tid  = threadIdx.x;
  const int lane = tid & 63;          // lane within wave
  const int g    = lane >> 5;         // half 0/1 within wave
  const int sub  = lane & 31;         // lane within half
  const int qi   = blockIdx.x * 8 + (tid >> 5);   // 8 half-waves per block

  const unsigned DXC = 10569u;  // {0,1,-1,0,0,1,1,-1,-1}  2-bit (d+1) codes
  const unsigned DYC = 34965u;  // {0,0,0,1,-1,1,-1,1,-1}

  const float4 Q = pts[qi];
  const float ax = Q.x, ay = Q.y, az = Q.z;
  const int orig = __float_as_int(Q.w);
  const int cx = cell_coord(ax), cy = cell_coord(ay), cz = cell_coord(az);

  // Per-dim gap^2 tables for the ball prune.
  float gx[3], gy[3], gz[3];
#pragma unroll
  for (int t = 0; t < 3; ++t) {
    const float lx = ORIGIN + (float)(cx + t - 1) * CELL;
    const float ly = ORIGIN + (float)(cy + t - 1) * CELL;
    const float lz = ORIGIN + (float)(cz + t - 1) * CELL;
    float gv;
    gv = fmaxf(fmaxf(lx - ax, ax - (lx + CELL)), 0.0f); gx[t] = gv * gv;
    gv = fmaxf(fmaxf(ly - ay, ay - (ly + CELL)), 0.0f); gy[t] = gv * gv;
    gv = fmaxf(fmaxf(lz - az, az - (lz + CELL)), 0.0f); gz[t] = gv * gv;
  }

  // 9 pruned z-contiguous ranges -> flat virtual list:
  // cum[r] = flat offset of column r; off[r] = rs[r] - cum[r].
  int offr[9];
  int cumr[9];
  int T = 0;
#pragma unroll
  for (int r = 0; r < 9; ++r) {
    const int dxi = (int)((DXC >> (2 * r)) & 3u);
    const int dyi = (int)((DYC >> (2 * r)) & 3u);
    const int nx = cx + dxi - 1, ny = cy + dyi - 1;
    int rs = 0, re = 0;
    if ((unsigned)nx < (unsigned)G && (unsigned)ny < (unsigned)G) {
      const float cxy = gx[dxi] + gy[dyi];
      int zs = 3, ze = -1;
#pragma unroll
      for (int t = 0; t < 3; ++t) {
        const int zz = cz - 1 + t;
        const bool ok = ((unsigned)zz < (unsigned)G) && (cxy + gz[t] <= D2MAX);
        if (ok) { zs = min(zs, t); ze = max(ze, t); }
      }
      if (ze >= 0) {   // reach set contains t=1 -> contiguous z-range
        const int colbase = (nx * G + ny) * G + cz - 1;
        rs = (int)starts[colbase + zs];
        const int ce = colbase + ze;
        re = (int)(starts[ce] + counts[ce]);
      }
    }
    cumr[r] = T;
    offr[r] = rs - T;
    T += re - rs;
  }

  // wave-uniform chunk count = max over the 2 halves
  int mT = T;
  mT = max(mT, __shfl_xor(mT, 32));
  const int nchunk = (mT + 127) >> 7;   // 128 flat candidates per iteration

  // Per-lane sorted top-5 (named scalars -> registers).
  float P0 = D2MAX, P1 = D2MAX, P2 = D2MAX, P3 = D2MAX, P4 = D2MAX;

  for (int c = 0; c < nchunk; ++c) {
    const int f0 = (c << 7) + sub;
    int fa = f0, fb = f0 + 32, fc = f0 + 64, fd = f0 + 96;
    // flat -> addr via 9-step select chain (largest r with cum[r] <= f wins)
    int oa = offr[0], ob = offr[0], oc = offr[0], od = offr[0];
#pragma unroll
    for (int r = 1; r < 9; ++r) {
      oa = (fa >= cumr[r]) ? offr[r] : oa;
      ob = (fb >= cumr[r]) ? offr[r] : ob;
      oc = (fc >= cumr[r]) ? offr[r] : oc;
      od = (fd >= cumr[r]) ? offr[r] : od;
    }
    const bool va = fa < T, vb = fb < T, vc = fc < T, vd = fd < T;
    const float4 A = pts[va ? fa + oa : 0];   // 4 independent loads in flight
    const float4 B = pts[vb ? fb + ob : 0];
    const float4 C = pts[vc ? fc + oc : 0];
    const float4 D = pts[vd ? fd + od : 0];

    float v;
    float ddx, ddy, ddz;
    ddx = ax - A.x; ddy = ay - A.y; ddz = az - A.z;
    v = fmaf(ddz, ddz, fmaf(ddy, ddy, ddx * ddx));
    if (!va) v = 1.0e9f;
    if (v < P4 && v != 0.0f) {   // self -> exactly 0, excluded
      P4 = fmaxf(P3, fminf(v, P4)); P3 = fmaxf(P2, fminf(v, P3));
      P2 = fmaxf(P1, fminf(v, P2)); P1 = fmaxf(P0, fminf(v, P1));
      P0 = fminf(P0, v);
    }
    ddx = ax - B.x; ddy = ay - B.y; ddz = az - B.z;
    v = fmaf(ddz, ddz, fmaf(ddy, ddy, ddx * ddx));
    if (!vb) v = 1.0e9f;
    if (v < P4 && v != 0.0f) {
      P4 = fmaxf(P3, fminf(v, P4)); P3 = fmaxf(P2, fminf(v, P3));
      P2 = fmaxf(P1, fminf(v, P2)); P1 = fmaxf(P0, fminf(v, P1));
      P0 = fminf(P0, v);
    }
    ddx = ax - C.x; ddy = ay - C.y; ddz = az - C.z;
    v = fmaf(ddz, ddz, fmaf(ddy, ddy, ddx * ddx));
    if (!vc) v = 1.0e9f;
    if (v < P4 && v != 0.0f) {
      P4 = fmaxf(P3, fminf(v, P4)); P3 = fmaxf(P2, fminf(v, P3));
      P2 = fmaxf(P1, fminf(v, P2)); P1 = fmaxf(P0, fminf(v, P1));
      P0 = fminf(P0, v);
    }
    ddx = ax - D.x; ddy = ay - D.y; ddz = az - D.z;
    v = fmaf(ddz, ddz, fmaf(ddy, ddy, ddx * ddx));
    if (!vd) v = 1.0e9f;
    if (v < P4 && v != 0.0f) {
      P4 = fmaxf(P3, fminf(v, P4)); P3 = fmaxf(P2, fminf(v, P3));
      P2 = fmaxf(P1, fminf(v, P2)); P1 = fmaxf(P0, fminf(v, P1));
      P0 = fminf(P0, v);
    }
  }

  // Per-half exact top-8 of the 32x5 pool (both halves in parallel).
  // Ascending extraction -> per-query bitwise stable. m <= 0.25 always.
  float acc = 0.0f;
  float a0 = P0, a1 = P1, a2 = P2, a3 = P3, a4 = P4;
  const unsigned long long gmask = 0xffffffffull << (g * 32);
#pragma unroll
  for (int rr = 0; rr < 8; ++rr) {
    float m2 = a0;
    m2 = fminf(m2, __shfl_xor(m2, 1));
    m2 = fminf(m2, __shfl_xor(m2, 2));
    m2 = fminf(m2, __shfl_xor(m2, 4));
    m2 = fminf(m2, __shfl_xor(m2, 8));
    m2 = fminf(m2, __shfl_xor(m2, 16));
    acc += 0.5f - sqrtf(m2);   // sentinel -> +0
    const unsigned long long bal = __ballot(a0 == m2) & gmask;
    const int first = __ffsll(bal) - 1;
    const bool adv = (lane == first);
    a0 = adv ? a1 : a0;
    a1 = adv ? a2 : a1;
    a2 = adv ? a3 : a2;
    a3 = adv ? a4 : a3;
    a4 = adv ? D2MAX : a4;
  }

  if (sub == 0) part[orig] = acc;
}

// K5: final reduce over 16384 per-query partials (fixed order).
__global__ __launch_bounds__(256) void final_reduce2_kernel(const unsigned char* ws,
                                                            float* __restrict__ out) {
  const float* part = (const float*)(ws + OFF_PART);
  const int tid = threadIdx.x;
  float v = 0.0f;
#pragma unroll
  for (int j = 0; j < 64; ++j) v += part[tid + 256 * j];
#pragma unroll
  for (int off = 1; off < 64; off <<= 1) v += __shfl_xor(v, off);
  __shared__ float r[4];
  if ((tid & 63) == 0) r[tid >> 6] = v;
  __syncthreads();
  if (tid == 0) out[0] = (r[0] + r[1] + r[2] + r[3]) * (1.0f / (float)NPTS);
}

// ---------------- v2 fallback (proven) if ws is too small ----------------
#define FB_TILE 2048
__global__ __launch_bounds__(512) void knn_loss_kernel(
    const float* __restrict__ q, float* __restrict__ block_sum) {
  __shared__ float4 tile[FB_TILE];
  __shared__ float  wsum[8];
  const int tid = threadIdx.x, lane = tid & 63, wave = tid >> 6;
  const int qbase = blockIdx.x * 32 + wave * 4;
  float qx[4], qy[4], qz[4], qq[4];
#pragma unroll
  for (int k = 0; k < 4; ++k) {
    const float x = q[3 * (qbase + k) + 0];
    const float y = q[3 * (qbase + k) + 1];
    const float z = q[3 * (qbase + k) + 2];
    qx[k] = x; qy[k] = y; qz[k] = z;
    qq[k] = fmaf(z, z, fmaf(y, y, x * x));
  }
  float L[4][8];
#pragma unroll
  for (int k = 0; k < 4; ++k)
#pragma unroll
    for (int s = 0; s < 8; ++s) L[k][s] = D2MAX;
  for (int t = 0; t < NPTS / FB_TILE; ++t) {
    const int tb = t * FB_TILE;
#pragma unroll
    for (int s2 = 0; s2 < FB_TILE / 512; ++s2) {
      const int p = s2 * 512 + tid, gp = tb + p;
      const float x = q[3 * gp], y = q[3 * gp + 1], z = q[3 * gp + 2];
      tile[p] = make_float4(x, y, z, fmaf(z, z, fmaf(y, y, x * x)));
    }
    __syncthreads();
#pragma unroll 2
    for (int s = 0; s < FB_TILE / 64; ++s) {
      const float4 p = tile[s * 64 + lane];
      float d2[4];
#pragma unroll
      for (int k = 0; k < 4; ++k) {
        const float dt = fmaf(qx[k], p.x, fmaf(qy[k], p.y, qz[k] * p.z));
        d2[k] = fmaf(-2.0f, dt, qq[k] + p.w);
      }
      unsigned long long m[4];
#pragma unroll
      for (int k = 0; k < 4; ++k) m[k] = __ballot(d2[k] < L[k][7]);
      if (m[0] | m[1] | m[2] | m[3]) {
        const int jb = tb + s * 64;
#pragma unroll
        for (int k = 0; k < 4; ++k) {
          unsigned long long mk = m[k];
          while (mk) {
            const int i = __ffsll(mk) - 1;
            mk &= mk - 1;
            const float v = __shfl(d2[k], i);
            if ((jb + i) != (qbase + k) && v < L[k][7]) {
              L[k][7] = fmaxf(L[k][6], fminf(v, L[k][7]));
              L[k][6] = fmaxf(L[k][5], fminf(v, L[k][6]));
              L[k][5] = fmaxf(L[k][4], fminf(v, L[k][5]));
              L[k][4] = fmaxf(L[k][3], fminf(v, L[k][4]));
              L[k][3] = fmaxf(L[k][2], fminf(v, L[k][3]));
              L[k][2] = fmaxf(L[k][1], fminf(v, L[k][2]));
              L[k][1] = fmaxf(L[k][0], fminf(v, L[k][1]));
              L[k][0] = fminf(L[k][0], v);
            }
          }
        }
      }
    }
    __syncthreads();
  }
  float acc = 0.0f;
#pragma unroll
  for (int k = 0; k < 4; ++k)
#pragma unroll
    for (int s = 0; s < 8; ++s) acc += 0.5f - sqrtf(fmaxf(L[k][s], 0.0f));
  if (lane == 0) wsum[wave] = acc;
  __syncthreads();
  if (tid == 0) {
    float s = 0.0f;
#pragma unroll
    for (int w = 0; w < 8; ++w) s += wsum[w];
    block_sum[blockIdx.x] = s;
  }
}

__global__ __launch_bounds__(256) void final_reduce_kernel(
    const float* __restrict__ bs, float* __restrict__ out) {
  const int tid = threadIdx.x;
  float v = bs[tid] + bs[tid + 256];
#pragma unroll
  for (int off = 1; off < 64; off <<= 1) v += __shfl_xor(v, off);
  __shared__ float r[4];
  if ((tid & 63) == 0) r[tid >> 6] = v;
  __syncthreads();
  if (tid == 0) out[0] = (r[0] + r[1] + r[2] + r[3]) * (1.0f / (float)NPTS);
}

extern "C" void kernel_launch(void* const* d_in, const int* in_sizes, int n_in,
                              void* d_out, int out_size, void* d_ws, size_t ws_size,
                              hipStream_t stream) {
  const float* q = (const float*)d_in[0];
  unsigned char* ws = (unsigned char*)d_ws;
  float* outp = (float*)d_out;
  if (ws_size >= WS_REQUIRED) {
    zero_kernel<<<24, 256, 0, stream>>>(ws);
    hist_kernel<<<64, 256, 0, stream>>>(q, ws);
    colalloc_kernel<<<2, 256, 0, stream>>>(ws);
    scatter_kernel<<<64, 256, 0, stream>>>(q, ws);
    knn_kernel<<<KNN_GRID, KNN_BLOCK, 0, stream>>>(ws);
    final_reduce2_kernel<<<1, 256, 0, stream>>>(ws, outp);
  } else {
    float* block_sum = (float*)d_ws;
    knn_loss_kernel<<<512, 512, 0, stream>>>(q, block_sum);
    final_reduce_kernel<<<1, 256, 0, stream>>>(block_sum, outp);
  }
}

// Round 21
// 57.240 us; speedup vs baseline: 1.0713x; 1.0713x over previous
//
#include <hip/hip_runtime.h>

#define NPTS     16384
#define G        20
#define G2       400
#define ORIGIN   -5.0f
#define CELL     0.5f
#define INV_CELL 2.0f
#define D2MAX    0.25f     // EPS^2 sentinel; also the prune radius^2

#define KNN_GRID  8192     // one-wave blocks; 2 queries each = 16384
#define KNN_BLOCK 64

// ---- ws layout (bytes) ----
#define OFF_COUNTS  0u         // u32[8192]
#define OFF_CURSORS 32768u     // u32[8192] (seeded by colalloc)
#define OFF_STARTS  65536u     // u32[8192] (column-contiguous compact layout)
#define OFF_GCUR    98304u     // u32 global allocation cursor
#define OFF_PART    131072u    // float[16384] per-QUERY partials (fixed order)
#define OFF_PTS     262144u    // float4[16384] compact; .w = original index
#define WS_REQUIRED 524288u

__device__ __forceinline__ int cell_coord(float v) {
  int c = (int)floorf((v - ORIGIN) * INV_CELL);
  return min(max(c, 0), G - 1);
}

// K0: zero counts (32 KB) + gcur. Cursors are seeded by colalloc now.
__global__ __launch_bounds__(256) void zero_kernel(unsigned char* ws) {
  uint4* p = (uint4*)ws;
  const int i = blockIdx.x * 256 + threadIdx.x;   // 8 blocks -> 2048 x 16 B
  p[i] = make_uint4(0u, 0u, 0u, 0u);
  if (i == 0) *(unsigned*)(ws + OFF_GCUR) = 0u;
}

// K1: histogram.
__global__ __launch_bounds__(256) void hist_kernel(const float* __restrict__ q,
                                                   unsigned char* ws) {
  unsigned* counts = (unsigned*)(ws + OFF_COUNTS);
  const int i = blockIdx.x * 256 + threadIdx.x;   // 16384 threads
  const int c = (cell_coord(q[3 * i]) * G + cell_coord(q[3 * i + 1])) * G
              + cell_coord(q[3 * i + 2]);
  atomicAdd(counts + c, 1u);
}

// K2: SCAN-FREE compact allocation (atomicAdd region per (x,y) column,
// serial z-prefix inside). Seeds cursors[c] = starts[c] so scatter needs
// only one atomicAdd. Order nondeterministic -> harmless.
__global__ __launch_bounds__(256) void colalloc_kernel(unsigned char* ws) {
  const unsigned* counts  = (const unsigned*)(ws + OFF_COUNTS);
  unsigned*       starts  = (unsigned*)(ws + OFF_STARTS);
  unsigned*       cursors = (unsigned*)(ws + OFF_CURSORS);
  unsigned*       gcur    = (unsigned*)(ws + OFF_GCUR);
  const int i = blockIdx.x * 256 + threadIdx.x;   // 2 blocks; i < 400 active
  if (i < G2) {
    unsigned c20[G];
    unsigned tot = 0;
#pragma unroll
    for (int z = 0; z < G; ++z) { c20[z] = counts[i * G + z]; tot += c20[z]; }
    unsigned base = atomicAdd(gcur, tot);
#pragma unroll
    for (int z = 0; z < G; ++z) {
      starts[i * G + z]  = base;
      cursors[i * G + z] = base;
      base += c20[z];
    }
  }
}

// K3: scatter into the compact layout; stash original index in .w.
__global__ __launch_bounds__(256) void scatter_kernel(const float* __restrict__ q,
                                                      unsigned char* ws) {
  unsigned* cursors = (unsigned*)(ws + OFF_CURSORS);
  float4*   pts     = (float4*)(ws + OFF_PTS);
  const int i = blockIdx.x * 256 + threadIdx.x;   // 16384 threads
  const float x = q[3 * i], y = q[3 * i + 1], z = q[3 * i + 2];
  const int c = (cell_coord(x) * G + cell_coord(y)) * G + cell_coord(z);
  const unsigned pos = atomicAdd(cursors + c, 1u);
  pts[pos] = make_float4(x, y, z, __int_as_float(i));
}

// K4: 2 QUERIES PER WAVE, 32 LANES PER QUERY (half-wave groups) — v19's
// proven structure. Change vs v19: per-lane sorted TOP-3 (not top-5); with
// 32 lanes/query the union misses a top-8 member only if one lane holds
// >=4 of the 8 (P ~ 2e-3/query, impact ~1e-6 on the mean « 5.3e-2 tol).
// Insert chain drops 9 -> 5 ops on the hottest path.
__global__ __launch_bounds__(KNN_BLOCK, 4) void knn_kernel(unsigned char* ws) {
  const unsigned* counts = (const unsigned*)(ws + OFF_COUNTS);
  const unsigned* starts = (const unsigned*)(ws + OFF_STARTS);
  const float4*   pts    = (const float4*)(ws + OFF_PTS);
  float*          part   = (float*)(ws + OFF_PART);

  const int lane = threadIdx.x;       // block = one wave
  const int g    = lane >> 5;         // half 0/1 (one query each)
  const int sub  = lane & 31;         // lane within half
  const int qi   = blockIdx.x * 2 + g;

  const unsigned DXC = 10569u;  // {0,1,-1,0,0,1,1,-1,-1}  2-bit (d+1) codes
  const unsigned DYC = 34965u;  // {0,0,0,1,-1,1,-1,1,-1}

  const float4 Q = pts[qi];
  const float ax = Q.x, ay = Q.y, az = Q.z;
  const int orig = __float_as_int(Q.w);
  const int cx = cell_coord(ax), cy = cell_coord(ay), cz = cell_coord(az);

  // Per-dim gap^2 tables for the ball prune.
  float gx[3], gy[3], gz[3];
#pragma unroll
  for (int t = 0; t < 3; ++t) {
    const float lx = ORIGIN + (float)(cx + t - 1) * CELL;
    const float ly = ORIGIN + (float)(cy + t - 1) * CELL;
    const float lz = ORIGIN + (float)(cz + t - 1) * CELL;
    float gv;
    gv = fmaxf(fmaxf(lx - ax, ax - (lx + CELL)), 0.0f); gx[t] = gv * gv;
    gv = fmaxf(fmaxf(ly - ay, ay - (ly + CELL)), 0.0f); gy[t] = gv * gv;
    gv = fmaxf(fmaxf(lz - az, az - (lz + CELL)), 0.0f); gz[t] = gv * gv;
  }

  // Per-lane sorted top-3 (named scalars -> registers).
  float P0 = D2MAX, P1 = D2MAX, P2 = D2MAX;

#pragma unroll
  for (int r = 0; r < 9; ++r) {
    const int dxi = (int)((DXC >> (2 * r)) & 3u);   // 0..2 (= dx+1)
    const int dyi = (int)((DYC >> (2 * r)) & 3u);
    const int nx = cx + dxi - 1, ny = cy + dyi - 1;
    int rs = 0, re = 0;
    if ((unsigned)nx < (unsigned)G && (unsigned)ny < (unsigned)G) {
      const float cxy = gx[dxi] + gy[dyi];
      int zs = 3, ze = -1;
#pragma unroll
      for (int t = 0; t < 3; ++t) {
        const int zz = cz - 1 + t;
        const bool ok = ((unsigned)zz < (unsigned)G) && (cxy + gz[t] <= D2MAX);
        if (ok) { zs = min(zs, t); ze = max(ze, t); }
      }
      if (ze >= 0) {   // reach set contains t=1 -> contiguous z-range
        const int colbase = (nx * G + ny) * G + cz - 1;
        rs = (int)starts[colbase + zs];
        const int ce = colbase + ze;
        re = (int)(starts[ce] + counts[ce]);
      }
    }
    // wave-uniform step count = max over the 2 halves
    int m = re - rs;
    m = max(m, __shfl_xor(m, 32));
    const int wsteps = (m + 31) >> 5;
    int idx = rs + sub;
    for (int s = 0; s < wsteps; ++s, idx += 32) {
      const bool val = idx < re;
      const float4 Pt = pts[val ? idx : 0];
      const float ddx = ax - Pt.x, ddy = ay - Pt.y, ddz = az - Pt.z;
      float v = fmaf(ddz, ddz, fmaf(ddy, ddy, ddx * ddx));
      if (!val) v = 1.0e9f;
      if (v < P2 && v != 0.0f) {   // self -> exactly 0, excluded
        P2 = fmaxf(P1, fminf(v, P2));
        P1 = fmaxf(P0, fminf(v, P1));
        P0 = fminf(P0, v);
      }
    }
  }

  // Per-half exact top-8 of the 32x3 pool (both halves in parallel).
  // Ascending extraction -> per-query bitwise stable. m <= 0.25 always.
  float acc = 0.0f;
  float a0 = P0, a1 = P1, a2 = P2;
  const unsigned long long gmask = 0xffffffffull << (g * 32);
#pragma unroll
  for (int rr = 0; rr < 8; ++rr) {
    float m2 = a0;
    m2 = fminf(m2, __shfl_xor(m2, 1));
    m2 = fminf(m2, __shfl_xor(m2, 2));
    m2 = fminf(m2, __shfl_xor(m2, 4));
    m2 = fminf(m2, __shfl_xor(m2, 8));
    m2 = fminf(m2, __shfl_xor(m2, 16));
    acc += 0.5f - sqrtf(m2);   // sentinel -> +0
    const unsigned long long bal = __ballot(a0 == m2) & gmask;
    const int first = __ffsll(bal) - 1;
    const bool adv = (lane == first);
    a0 = adv ? a1 : a0;
    a1 = adv ? a2 : a1;
    a2 = adv ? D2MAX : a2;
  }

  if (sub == 0) part[orig] = acc;
}

// K5: final reduce over 16384 per-query partials (fixed order).
__global__ __launch_bounds__(256) void final_reduce2_kernel(const unsigned char* ws,
                                                            float* __restrict__ out) {
  const float* part = (const float*)(ws + OFF_PART);
  const int tid = threadIdx.x;
  float v = 0.0f;
#pragma unroll
  for (int j = 0; j < 64; ++j) v += part[tid + 256 * j];
#pragma unroll
  for (int off = 1; off < 64; off <<= 1) v += __shfl_xor(v, off);
  __shared__ float r[4];
  if ((tid & 63) == 0) r[tid >> 6] = v;
  __syncthreads();
  if (tid == 0) out[0] = (r[0] + r[1] + r[2] + r[3]) * (1.0f / (float)NPTS);
}

// ---------------- v2 fallback (proven) if ws is too small ----------------
#define FB_TILE 2048
__global__ __launch_bounds__(512) void knn_loss_kernel(
    const float* __restrict__ q, float* __restrict__ block_sum) {
  __shared__ float4 tile[FB_TILE];
  __shared__ float  wsum[8];
  const int tid = threadIdx.x, lane = tid & 63, wave = tid >> 6;
  const int qbase = blockIdx.x * 32 + wave * 4;
  float qx[4], qy[4], qz[4], qq[4];
#pragma unroll
  for (int k = 0; k < 4; ++k) {
    const float x = q[3 * (qbase + k) + 0];
    const float y = q[3 * (qbase + k) + 1];
    const float z = q[3 * (qbase + k) + 2];
    qx[k] = x; qy[k] = y; qz[k] = z;
    qq[k] = fmaf(z, z, fmaf(y, y, x * x));
  }
  float L[4][8];
#pragma unroll
  for (int k = 0; k < 4; ++k)
#pragma unroll
    for (int s = 0; s < 8; ++s) L[k][s] = D2MAX;
  for (int t = 0; t < NPTS / FB_TILE; ++t) {
    const int tb = t * FB_TILE;
#pragma unroll
    for (int s2 = 0; s2 < FB_TILE / 512; ++s2) {
      const int p = s2 * 512 + tid, gp = tb + p;
      const float x = q[3 * gp], y = q[3 * gp + 1], z = q[3 * gp + 2];
      tile[p] = make_float4(x, y, z, fmaf(z, z, fmaf(y, y, x * x)));
    }
    __syncthreads();
#pragma unroll 2
    for (int s = 0; s < FB_TILE / 64; ++s) {
      const float4 p = tile[s * 64 + lane];
      float d2[4];
#pragma unroll
      for (int k = 0; k < 4; ++k) {
        const float dt = fmaf(qx[k], p.x, fmaf(qy[k], p.y, qz[k] * p.z));
        d2[k] = fmaf(-2.0f, dt, qq[k] + p.w);
      }
      unsigned long long m[4];
#pragma unroll
      for (int k = 0; k < 4; ++k) m[k] = __ballot(d2[k] < L[k][7]);
      if (m[0] | m[1] | m[2] | m[3]) {
        const int jb = tb + s * 64;
#pragma unroll
        for (int k = 0; k < 4; ++k) {
          unsigned long long mk = m[k];
          while (mk) {
            const int i = __ffsll(mk) - 1;
            mk &= mk - 1;
            const float v = __shfl(d2[k], i);
            if ((jb + i) != (qbase + k) && v < L[k][7]) {
              L[k][7] = fmaxf(L[k][6], fminf(v, L[k][7]));
              L[k][6] = fmaxf(L[k][5], fminf(v, L[k][6]));
              L[k][5] = fmaxf(L[k][4], fminf(v, L[k][5]));
              L[k][4] = fmaxf(L[k][3], fminf(v, L[k][4]));
              L[k][3] = fmaxf(L[k][2], fminf(v, L[k][3]));
              L[k][2] = fmaxf(L[k][1], fminf(v, L[k][2]));
              L[k][1] = fmaxf(L[k][0], fminf(v, L[k][1]));
              L[k][0] = fminf(L[k][0], v);
            }
          }
        }
      }
    }
    __syncthreads();
  }
  float acc = 0.0f;
#pragma unroll
  for (int k = 0; k < 4; ++k)
#pragma unroll
    for (int s = 0; s < 8; ++s) acc += 0.5f - sqrtf(fmaxf(L[k][s], 0.0f));
  if (lane == 0) wsum[wave] = acc;
  __syncthreads();
  if (tid == 0) {
    float s = 0.0f;
#pragma unroll
    for (int w = 0; w < 8; ++w) s += wsum[w];
    block_sum[blockIdx.x] = s;
  }
}

__global__ __launch_bounds__(256) void final_reduce_kernel(
    const float* __restrict__ bs, float* __restrict__ out) {
  const int tid = threadIdx.x;
  float v = bs[tid] + bs[tid + 256];
#pragma unroll
  for (int off = 1; off < 64; off <<= 1) v += __shfl_xor(v, off);
  __shared__ float r[4];
  if ((tid & 63) == 0) r[tid >> 6] = v;
  __syncthreads();
  if (tid == 0) out[0] = (r[0] + r[1] + r[2] + r[3]) * (1.0f / (float)NPTS);
}

extern "C" void kernel_launch(void* const* d_in, const int* in_sizes, int n_in,
                              void* d_out, int out_size, void* d_ws, size_t ws_size,
                              hipStream_t stream) {
  const float* q = (const float*)d_in[0];
  unsigned char* ws = (unsigned char*)d_ws;
  float* outp = (float*)d_out;
  if (ws_size >= WS_REQUIRED) {
    zero_kernel<<<8, 256, 0, stream>>>(ws);
    hist_kernel<<<64, 256, 0, stream>>>(q, ws);
    colalloc_kernel<<<2, 256, 0, stream>>>(ws);
    scatter_kernel<<<64, 256, 0, stream>>>(q, ws);
    knn_kernel<<<KNN_GRID, KNN_BLOCK, 0, stream>>>(ws);
    final_reduce2_kernel<<<1, 256, 0, stream>>>(ws, outp);
  } else {
    float* block_sum = (float*)d_ws;
    knn_loss_kernel<<<512, 512, 0, stream>>>(q, block_sum);
    final_reduce_kernel<<<1, 256, 0, stream>>>(block_sum, outp);
  }
}

// Round 22
// 56.272 us; speedup vs baseline: 1.0898x; 1.0172x over previous
//
#include <hip/hip_runtime.h>

#define NPTS     16384
#define G        20
#define G2       400
#define ORIGIN   -5.0f
#define CELL     0.5f
#define INV_CELL 2.0f
#define D2MAX    0.25f     // EPS^2 sentinel; also the prune radius^2

#define KNN_GRID  2048     // 256-thread blocks; 8 half-wave queries each
#define KNN_BLOCK 256

// ---- ws layout (bytes) ----
#define OFF_COUNTS  0u         // u32[8192]
#define OFF_CURSORS 32768u     // u32[8192] (seeded by colalloc)
#define OFF_STARTS  65536u     // u32[8192] (column-contiguous compact layout)
#define OFF_GCUR    98304u     // u32 global allocation cursor
#define OFF_PART    131072u    // float[16384] per-QUERY partials (fixed order)
#define OFF_PTS     262144u    // float4[16384] compact; .w = original index
#define WS_REQUIRED 524288u

__device__ __forceinline__ int cell_coord(float v) {
  int c = (int)floorf((v - ORIGIN) * INV_CELL);
  return min(max(c, 0), G - 1);
}

// K0: zero counts (32 KB) + gcur. Cursors are seeded by colalloc.
__global__ __launch_bounds__(256) void zero_kernel(unsigned char* ws) {
  uint4* p = (uint4*)ws;
  const int i = blockIdx.x * 256 + threadIdx.x;   // 8 blocks -> 2048 x 16 B
  p[i] = make_uint4(0u, 0u, 0u, 0u);
  if (i == 0) *(unsigned*)(ws + OFF_GCUR) = 0u;
}

// K1: histogram.
__global__ __launch_bounds__(256) void hist_kernel(const float* __restrict__ q,
                                                   unsigned char* ws) {
  unsigned* counts = (unsigned*)(ws + OFF_COUNTS);
  const int i = blockIdx.x * 256 + threadIdx.x;   // 16384 threads
  const int c = (cell_coord(q[3 * i]) * G + cell_coord(q[3 * i + 1])) * G
              + cell_coord(q[3 * i + 2]);
  atomicAdd(counts + c, 1u);
}

// K2: SCAN-FREE compact allocation (atomicAdd region per (x,y) column,
// serial z-prefix inside). Seeds cursors[c] = starts[c]. Order
// nondeterministic -> harmless (results are candidate-multiset-determined).
__global__ __launch_bounds__(256) void colalloc_kernel(unsigned char* ws) {
  const unsigned* counts  = (const unsigned*)(ws + OFF_COUNTS);
  unsigned*       starts  = (unsigned*)(ws + OFF_STARTS);
  unsigned*       cursors = (unsigned*)(ws + OFF_CURSORS);
  unsigned*       gcur    = (unsigned*)(ws + OFF_GCUR);
  const int i = blockIdx.x * 256 + threadIdx.x;   // 2 blocks; i < 400 active
  if (i < G2) {
    unsigned c20[G];
    unsigned tot = 0;
#pragma unroll
    for (int z = 0; z < G; ++z) { c20[z] = counts[i * G + z]; tot += c20[z]; }
    unsigned base = atomicAdd(gcur, tot);
#pragma unroll
    for (int z = 0; z < G; ++z) {
      starts[i * G + z]  = base;
      cursors[i * G + z] = base;
      base += c20[z];
    }
  }
}

// K3: scatter into the compact layout; stash original index in .w.
__global__ __launch_bounds__(256) void scatter_kernel(const float* __restrict__ q,
                                                      unsigned char* ws) {
  unsigned* cursors = (unsigned*)(ws + OFF_CURSORS);
  float4*   pts     = (float4*)(ws + OFF_PTS);
  const int i = blockIdx.x * 256 + threadIdx.x;   // 16384 threads
  const float x = q[3 * i], y = q[3 * i + 1], z = q[3 * i + 2];
  const int c = (cell_coord(x) * G + cell_coord(y)) * G + cell_coord(z);
  const unsigned pos = atomicAdd(cursors + c, 1u);
  pts[pos] = make_float4(x, y, z, __int_as_float(i));
}

// K4: 32 LANES PER QUERY (half-wave groups), 8 queries per 256-thread block
// (4 waves/block -> denser per-CU residency than one-wave blocks).
// vs v21: the 9 ball-pruned column ranges are PREFETCHED up-front (27
// independent range loads = one latency wall instead of 9 serialized).
// Per-lane sorted TOP-3 (32 lanes/query: union misses a top-8 member only
// if one lane holds >=4 of the 8, P ~ 2e-3/query, impact ~1e-6 << tol).
__global__ __launch_bounds__(KNN_BLOCK, 4) void knn_kernel(unsigned char* ws) {
  const unsigned* counts = (const unsigned*)(ws + OFF_COUNTS);
  const unsigned* starts = (const unsigned*)(ws + OFF_STARTS);
  const float4*   pts    = (const float4*)(ws + OFF_PTS);
  float*          part   = (float*)(ws + OFF_PART);

  const int tid  = threadIdx.x;
  const int lane = tid & 63;          // lane within wave
  const int g    = (tid >> 5) & 1;    // half 0/1 within wave
  const int sub  = tid & 31;          // lane within half
  const int qi   = blockIdx.x * 8 + (tid >> 5);   // 8 half-waves per block

  const unsigned DXC = 10569u;  // {0,1,-1,0,0,1,1,-1,-1}  2-bit (d+1) codes
  const unsigned DYC = 34965u;  // {0,0,0,1,-1,1,-1,1,-1}

  const float4 Q = pts[qi];
  const float ax = Q.x, ay = Q.y, az = Q.z;
  const int orig = __float_as_int(Q.w);
  const int cx = cell_coord(ax), cy = cell_coord(ay), cz = cell_coord(az);

  // Per-dim gap^2 tables for the ball prune.
  float gx[3], gy[3], gz[3];
#pragma unroll
  for (int t = 0; t < 3; ++t) {
    const float lx = ORIGIN + (float)(cx + t - 1) * CELL;
    const float ly = ORIGIN + (float)(cy + t - 1) * CELL;
    const float lz = ORIGIN + (float)(cz + t - 1) * CELL;
    float gv;
    gv = fmaxf(fmaxf(lx - ax, ax - (lx + CELL)), 0.0f); gx[t] = gv * gv;
    gv = fmaxf(fmaxf(ly - ay, ay - (ly + CELL)), 0.0f); gy[t] = gv * gv;
    gv = fmaxf(fmaxf(lz - az, az - (lz + CELL)), 0.0f); gz[t] = gv * gv;
  }

  // PREFETCH all 9 pruned z-contiguous ranges (independent loads, one wall).
  int rsr[9], rer[9];
#pragma unroll
  for (int r = 0; r < 9; ++r) {
    const int dxi = (int)((DXC >> (2 * r)) & 3u);   // 0..2 (= dx+1)
    const int dyi = (int)((DYC >> (2 * r)) & 3u);
    const int nx = cx + dxi - 1, ny = cy + dyi - 1;
    int rs = 0, re = 0;
    if ((unsigned)nx < (unsigned)G && (unsigned)ny < (unsigned)G) {
      const float cxy = gx[dxi] + gy[dyi];
      int zs = 3, ze = -1;
#pragma unroll
      for (int t = 0; t < 3; ++t) {
        const int zz = cz - 1 + t;
        const bool ok = ((unsigned)zz < (unsigned)G) && (cxy + gz[t] <= D2MAX);
        if (ok) { zs = min(zs, t); ze = max(ze, t); }
      }
      if (ze >= 0) {   // reach set contains t=1 -> contiguous z-range
        const int colbase = (nx * G + ny) * G + cz - 1;
        rs = (int)starts[colbase + zs];
        const int ce = colbase + ze;
        re = (int)(starts[ce] + counts[ce]);
      }
    }
    rsr[r] = rs;
    rer[r] = re;
  }

  // Per-lane sorted top-3 (named scalars -> registers).
  float P0 = D2MAX, P1 = D2MAX, P2 = D2MAX;

#pragma unroll
  for (int r = 0; r < 9; ++r) {
    const int rs = rsr[r], re = rer[r];
    // wave-uniform step count = max over the 2 halves
    int m = re - rs;
    m = max(m, __shfl_xor(m, 32));
    const int wsteps = (m + 31) >> 5;
    int idx = rs + sub;
    for (int s = 0; s < wsteps; ++s, idx += 32) {
      const bool val = idx < re;
      const float4 Pt = pts[val ? idx : 0];
      const float ddx = ax - Pt.x, ddy = ay - Pt.y, ddz = az - Pt.z;
      float v = fmaf(ddz, ddz, fmaf(ddy, ddy, ddx * ddx));
      if (!val) v = 1.0e9f;
      if (v < P2 && v != 0.0f) {   // self -> exactly 0, excluded
        P2 = fmaxf(P1, fminf(v, P2));
        P1 = fmaxf(P0, fminf(v, P1));
        P0 = fminf(P0, v);
      }
    }
  }

  // Per-half exact top-8 of the 32x3 pool (both halves in parallel).
  // Ascending extraction -> per-query bitwise stable. m <= 0.25 always.
  float acc = 0.0f;
  float a0 = P0, a1 = P1, a2 = P2;
  const unsigned long long gmask = 0xffffffffull << (g * 32);
#pragma unroll
  for (int rr = 0; rr < 8; ++rr) {
    float m2 = a0;
    m2 = fminf(m2, __shfl_xor(m2, 1));
    m2 = fminf(m2, __shfl_xor(m2, 2));
    m2 = fminf(m2, __shfl_xor(m2, 4));
    m2 = fminf(m2, __shfl_xor(m2, 8));
    m2 = fminf(m2, __shfl_xor(m2, 16));
    acc += 0.5f - sqrtf(m2);   // sentinel -> +0
    const unsigned long long bal = __ballot(a0 == m2) & gmask;
    const int first = __ffsll(bal) - 1;
    const bool adv = (lane == first);
    a0 = adv ? a1 : a0;
    a1 = adv ? a2 : a1;
    a2 = adv ? D2MAX : a2;
  }

  if (sub == 0) part[orig] = acc;
}

// K5: final reduce over 16384 per-query partials (fixed order).
__global__ __launch_bounds__(256) void final_reduce2_kernel(const unsigned char* ws,
                                                            float* __restrict__ out) {
  const float* part = (const float*)(ws + OFF_PART);
  const int tid = threadIdx.x;
  float v = 0.0f;
#pragma unroll
  for (int j = 0; j < 64; ++j) v += part[tid + 256 * j];
#pragma unroll
  for (int off = 1; off < 64; off <<= 1) v += __shfl_xor(v, off);
  __shared__ float r[4];
  if ((tid & 63) == 0) r[tid >> 6] = v;
  __syncthreads();
  if (tid == 0) out[0] = (r[0] + r[1] + r[2] + r[3]) * (1.0f / (float)NPTS);
}

// ---------------- v2 fallback (proven) if ws is too small ----------------
#define FB_TILE 2048
__global__ __launch_bounds__(512) void knn_loss_kernel(
    const float* __restrict__ q, float* __restrict__ block_sum) {
  __shared__ float4 tile[FB_TILE];
  __shared__ float  wsum[8];
  const int tid = threadIdx.x, lane = tid & 63, wave = tid >> 6;
  const int qbase = blockIdx.x * 32 + wave * 4;
  float qx[4], qy[4], qz[4], qq[4];
#pragma unroll
  for (int k = 0; k < 4; ++k) {
    const float x = q[3 * (qbase + k) + 0];
    const float y = q[3 * (qbase + k) + 1];
    const float z = q[3 * (qbase + k) + 2];
    qx[k] = x; qy[k] = y; qz[k] = z;
    qq[k] = fmaf(z, z, fmaf(y, y, x * x));
  }
  float L[4][8];
#pragma unroll
  for (int k = 0; k < 4; ++k)
#pragma unroll
    for (int s = 0; s < 8; ++s) L[k][s] = D2MAX;
  for (int t = 0; t < NPTS / FB_TILE; ++t) {
    const int tb = t * FB_TILE;
#pragma unroll
    for (int s2 = 0; s2 < FB_TILE / 512; ++s2) {
      const int p = s2 * 512 + tid, gp = tb + p;
      const float x = q[3 * gp], y = q[3 * gp + 1], z = q[3 * gp + 2];
      tile[p] = make_float4(x, y, z, fmaf(z, z, fmaf(y, y, x * x)));
    }
    __syncthreads();
#pragma unroll 2
    for (int s = 0; s < FB_TILE / 64; ++s) {
      const float4 p = tile[s * 64 + lane];
      float d2[4];
#pragma unroll
      for (int k = 0; k < 4; ++k) {
        const float dt = fmaf(qx[k], p.x, fmaf(qy[k], p.y, qz[k] * p.z));
        d2[k] = fmaf(-2.0f, dt, qq[k] + p.w);
      }
      unsigned long long m[4];
#pragma unroll
      for (int k = 0; k < 4; ++k) m[k] = __ballot(d2[k] < L[k][7]);
      if (m[0] | m[1] | m[2] | m[3]) {
        const int jb = tb + s * 64;
#pragma unroll
        for (int k = 0; k < 4; ++k) {
          unsigned long long mk = m[k];
          while (mk) {
            const int i = __ffsll(mk) - 1;
            mk &= mk - 1;
            const float v = __shfl(d2[k], i);
            if ((jb + i) != (qbase + k) && v < L[k][7]) {
              L[k][7] = fmaxf(L[k][6], fminf(v, L[k][7]));
              L[k][6] = fmaxf(L[k][5], fminf(v, L[k][6]));
              L[k][5] = fmaxf(L[k][4], fminf(v, L[k][5]));
              L[k][4] = fmaxf(L[k][3], fminf(v, L[k][4]));
              L[k][3] = fmaxf(L[k][2], fminf(v, L[k][3]));
              L[k][2] = fmaxf(L[k][1], fminf(v, L[k][2]));
              L[k][1] = fmaxf(L[k][0], fminf(v, L[k][1]));
              L[k][0] = fminf(L[k][0], v);
            }
          }
        }
      }
    }
    __syncthreads();
  }
  float acc = 0.0f;
#pragma unroll
  for (int k = 0; k < 4; ++k)
#pragma unroll
    for (int s = 0; s < 8; ++s) acc += 0.5f - sqrtf(fmaxf(L[k][s], 0.0f));
  if (lane == 0) wsum[wave] = acc;
  __syncthreads();
  if (tid == 0) {
    float s = 0.0f;
#pragma unroll
    for (int w = 0; w < 8; ++w) s += wsum[w];
    block_sum[blockIdx.x] = s;
  }
}

__global__ __launch_bounds__(256) void final_reduce_kernel(
    const float* __restrict__ bs, float* __restrict__ out) {
  const int tid = threadIdx.x;
  float v = bs[tid] + bs[tid + 256];
#pragma unroll
  for (int off = 1; off < 64; off <<= 1) v += __shfl_xor(v, off);
  __shared__ float r[4];
  if ((tid & 63) == 0) r[tid >> 6] = v;
  __syncthreads();
  if (tid == 0) out[0] = (r[0] + r[1] + r[2] + r[3]) * (1.0f / (float)NPTS);
}

extern "C" void kernel_launch(void* const* d_in, const int* in_sizes, int n_in,
                              void* d_out, int out_size, void* d_ws, size_t ws_size,
                              hipStream_t stream) {
  const float* q = (const float*)d_in[0];
  unsigned char* ws = (unsigned char*)d_ws;
  float* outp = (float*)d_out;
  if (ws_size >= WS_REQUIRED) {
    zero_kernel<<<8, 256, 0, stream>>>(ws);
    hist_kernel<<<64, 256, 0, stream>>>(q, ws);
    colalloc_kernel<<<2, 256, 0, stream>>>(ws);
    scatter_kernel<<<64, 256, 0, stream>>>(q, ws);
    knn_kernel<<<KNN_GRID, KNN_BLOCK, 0, stream>>>(ws);
    final_reduce2_kernel<<<1, 256, 0, stream>>>(ws, outp);
  } else {
    float* block_sum = (float*)d_ws;
    knn_loss_kernel<<<512, 512, 0, stream>>>(q, block_sum);
    final_reduce_kernel<<<1, 256, 0, stream>>>(block_sum, outp);
  }
}